// Round 1
// baseline (551.678 us; speedup 1.0000x reference)
//
#include <hip/hip_runtime.h>
#include <hip/hip_bf16.h>

// Problem constants
#define B_ROWS 32768
#define K_DIM  512
#define NP     1536   // packed qkv width per input

typedef __attribute__((ext_vector_type(8))) short          bf16x8;
typedef __attribute__((ext_vector_type(8))) unsigned short u16x8;
typedef __attribute__((ext_vector_type(4))) unsigned short u16x4;
typedef __attribute__((ext_vector_type(4))) float          f32x4;

static __device__ __forceinline__ unsigned short f2bf(float f) {
  __hip_bfloat16 h = __float2bfloat16(f);
  unsigned short u; __builtin_memcpy(&u, &h, 2); return u;
}
static __device__ __forceinline__ float bf2f(unsigned short u) {
  unsigned int x = ((unsigned int)u) << 16; float f; __builtin_memcpy(&f, &x, 4); return f;
}

// async global->LDS, 16B per lane. Dest base must be wave-uniform; HW adds lane*16B.
static __device__ __forceinline__ void gload_lds16(const void* g, void* l) {
  __builtin_amdgcn_global_load_lds(
      (const __attribute__((address_space(1))) void*)g,
      (__attribute__((address_space(3))) void*)l, 16, 0, 0);
}

// ---------------------------------------------------------------------------
// K0: pack weights to bf16 (row-major [n][k], MFMA-B-ready) + pack biases fp32
//   Wp = [Wq1; Wk2; Wv2]  (protein-input projections)
//   Wl = [Wk1; Wv1; Wq2]  (ligand-input projections)
// ---------------------------------------------------------------------------
__global__ __launch_bounds__(256) void pack_kernel(
    const float* __restrict__ Wq1, const float* __restrict__ Wk1,
    const float* __restrict__ Wv1, const float* __restrict__ Wq2,
    const float* __restrict__ Wk2, const float* __restrict__ Wv2,
    const float* __restrict__ Wo1, const float* __restrict__ Wo2,
    const float* __restrict__ bq1, const float* __restrict__ bk1,
    const float* __restrict__ bv1, const float* __restrict__ bq2,
    const float* __restrict__ bk2, const float* __restrict__ bv2,
    unsigned short* __restrict__ Wp, unsigned short* __restrict__ Wl,
    unsigned short* __restrict__ Wo1b, unsigned short* __restrict__ Wo2b,
    float* __restrict__ bp, float* __restrict__ bl)
{
  const int gid = blockIdx.x * 256 + threadIdx.x;   // 524288 threads
  const int idx = gid * 4;                          // 4 floats each
  const float* src; unsigned short* dst;
  if (idx < 786432) {                               // Wp
    int n = idx >> 9, k = idx & 511;
    const float* W = (n < 512) ? (Wq1 + (size_t)n * 512)
                   : (n < 1024) ? (Wk2 + (size_t)(n - 512) * 512)
                                : (Wv2 + (size_t)(n - 1024) * 512);
    src = W + k; dst = Wp + idx;
  } else if (idx < 1572864) {                       // Wl
    int r = idx - 786432; int n = r >> 9, k = r & 511;
    const float* W = (n < 512) ? (Wk1 + (size_t)n * 512)
                   : (n < 1024) ? (Wv1 + (size_t)(n - 512) * 512)
                                : (Wq2 + (size_t)(n - 1024) * 512);
    src = W + k; dst = Wl + r;
  } else if (idx < 1835008) {                       // Wo1
    int r = idx - 1572864; src = Wo1 + r; dst = Wo1b + r;
  } else {                                          // Wo2
    int r = idx - 1835008; src = Wo2 + r; dst = Wo2b + r;
  }
  float4 v = *reinterpret_cast<const float4*>(src);
  u16x4 o; o[0] = f2bf(v.x); o[1] = f2bf(v.y); o[2] = f2bf(v.z); o[3] = f2bf(v.w);
  *reinterpret_cast<u16x4*>(dst) = o;

  if (gid < 1536) {
    int n = gid;
    bp[n] = (n < 512) ? bq1[n] : (n < 1024) ? bk2[n - 512] : bv2[n - 1024];
  } else if (gid < 3072) {
    int n = gid - 1536;
    bl[n] = (n < 512) ? bk1[n] : (n < 1024) ? bv1[n - 512] : bq2[n - 1024];
  }
}

// ---------------------------------------------------------------------------
// GEMM: C[m][n] = sum_k A[m][k] * W[n][k] + bias[n]
//   128x128 tile, BK=32, 256 threads (4 waves, 2x2), MFMA 16x16x32 bf16.
//   A_F32: A is fp32, reg-staged with conversion; else bf16 via global_load_lds.
//   B always bf16 [n][k] via global_load_lds (dest byte = 16*t, linear).
// ---------------------------------------------------------------------------
template<bool A_F32, bool OUT_F32>
__global__ __launch_bounds__(256, 2)
void gemm_kernel(const void* __restrict__ Aptr, int lda,
                 const unsigned short* __restrict__ Wb,
                 const float* __restrict__ bias,
                 void* __restrict__ Cptr, int ldc,
                 int ntiles)
{
  __shared__ __align__(16) unsigned short As[128 * 32];
  __shared__ __align__(16) unsigned short Bs[128 * 32];

  // bijective XCD swizzle (gridDim.x % 8 == 0 guaranteed by launch)
  const int nwg = gridDim.x;
  const int cpx = nwg >> 3;
  const int b0  = blockIdx.x;
  const int wk  = (b0 & 7) * cpx + (b0 >> 3);
  const int mt  = wk / ntiles, nt = wk - mt * ntiles;
  const int m0  = mt << 7, n0 = nt << 7;

  const int tid = threadIdx.x;
  const int lane = tid & 63, w = tid >> 6;
  const int wm = w >> 1, wn = w & 1;
  const int fr = lane & 15, fk = lane >> 4;     // frag row/col select, k-chunk

  f32x4 acc[4][4] = {};

  const int arow = tid >> 1, akh = tid & 1;     // A fp32 staging map

  for (int kk = 0; kk < 512; kk += 32) {
    // --- stage B tile [128n x 32k] via global_load_lds (2 rounds) ---
#pragma unroll
    for (int r = 0; r < 2; ++r) {
      const int t = r * 256 + tid;
      const unsigned short* src = Wb + (size_t)(n0 + (t >> 2)) * 512 + kk + (t & 3) * 8;
      gload_lds16(src, &Bs[r * 2048 + w * 512]);
    }
    // --- stage A tile [128m x 32k] ---
    if (A_F32) {
      const float* s = (const float*)Aptr + (size_t)(m0 + arow) * lda + kk + akh * 16;
      float4 v0 = ((const float4*)s)[0];
      float4 v1 = ((const float4*)s)[1];
      float4 v2 = ((const float4*)s)[2];
      float4 v3 = ((const float4*)s)[3];
      u16x8 p0, p1;
      p0[0] = f2bf(v0.x); p0[1] = f2bf(v0.y); p0[2] = f2bf(v0.z); p0[3] = f2bf(v0.w);
      p0[4] = f2bf(v1.x); p0[5] = f2bf(v1.y); p0[6] = f2bf(v1.z); p0[7] = f2bf(v1.w);
      p1[0] = f2bf(v2.x); p1[1] = f2bf(v2.y); p1[2] = f2bf(v2.z); p1[3] = f2bf(v2.w);
      p1[4] = f2bf(v3.x); p1[5] = f2bf(v3.y); p1[6] = f2bf(v3.z); p1[7] = f2bf(v3.w);
      *(u16x8*)&As[arow * 32 + akh * 16]     = p0;
      *(u16x8*)&As[arow * 32 + akh * 16 + 8] = p1;
    } else {
#pragma unroll
      for (int r = 0; r < 2; ++r) {
        const int t = r * 256 + tid;
        const unsigned short* src = (const unsigned short*)Aptr +
            (size_t)(m0 + (t >> 2)) * lda + kk + (t & 3) * 8;
        gload_lds16(src, &As[r * 2048 + w * 512]);
      }
    }
    __syncthreads();   // drains vmcnt (global_load_lds) + lgkm (ds_write)

    bf16x8 af[4], bfr[4];
#pragma unroll
    for (int i = 0; i < 4; ++i) {
      af[i]  = *(const bf16x8*)&As[(wm * 64 + i * 16 + fr) * 32 + fk * 8];
      bfr[i] = *(const bf16x8*)&Bs[(wn * 64 + i * 16 + fr) * 32 + fk * 8];
    }
#pragma unroll
    for (int mi = 0; mi < 4; ++mi)
#pragma unroll
      for (int ni = 0; ni < 4; ++ni)
        acc[mi][ni] = __builtin_amdgcn_mfma_f32_16x16x32_bf16(af[mi], bfr[ni], acc[mi][ni], 0, 0, 0);
    __syncthreads();
  }

  // --- epilogue: bias add, store. C layout: col = lane&15, row = (lane>>4)*4 + j ---
#pragma unroll
  for (int ni = 0; ni < 4; ++ni) {
    const int col = n0 + wn * 64 + ni * 16 + fr;
    const float bv = bias[col];
#pragma unroll
    for (int mi = 0; mi < 4; ++mi) {
      const int rbase = m0 + wm * 64 + mi * 16 + fk * 4;
#pragma unroll
      for (int j = 0; j < 4; ++j) {
        const float v = acc[mi][ni][j] + bv;
        if (OUT_F32)
          ((float*)Cptr)[(size_t)(rbase + j) * ldc + col] = v;
        else
          ((unsigned short*)Cptr)[(size_t)(rbase + j) * ldc + col] = f2bf(v);
      }
    }
  }
}

// ---------------------------------------------------------------------------
// K2: per-row head-mixing attention, both directions. 1 wave = 1 row.
//   qkvp rows: [q1 | k2 | v2], qkvl rows: [k1 | v1 | q2] (bf16, stride 1536).
//   att1 overwrites qkvp[:,0:512], att2 overwrites qkvl[:,0:512].
// ---------------------------------------------------------------------------
__global__ __launch_bounds__(256, 4)
void attn_kernel(unsigned short* __restrict__ qkvp, unsigned short* __restrict__ qkvl)
{
  __shared__ float lds[4][1696];  // per wave: Q[8][68], K[8][68], V[8][68], ATT[64]
  const int w = threadIdx.x >> 6, lane = threadIdx.x & 63;
  const size_t r = (size_t)blockIdx.x * 4 + w;
  unsigned short* rp = qkvp + r * NP;
  unsigned short* rl = qkvl + r * NP;
  const int l8 = lane * 8;

  // load all six 512-wide row segments up-front (16B/lane each, coalesced)
  u16x8 q1 = *(const u16x8*)(rp + l8);
  u16x8 k2 = *(const u16x8*)(rp + 512 + l8);
  u16x8 v2 = *(const u16x8*)(rp + 1024 + l8);
  u16x8 k1 = *(const u16x8*)(rl + l8);
  u16x8 v1 = *(const u16x8*)(rl + 512 + l8);
  u16x8 q2 = *(const u16x8*)(rl + 1024 + l8);

  float* Q   = &lds[w][0];
  float* Kk  = Q + 544;
  float* V   = Kk + 544;
  float* ATT = V + 544;
  const int h = lane >> 3, e = lane & 7;
  const int sb = h * 68 + (lane & 7) * 8;   // this lane's 8 elems: head=lane>>3, d=(lane&7)*8

  auto stage = [&](u16x8 qv, u16x8 kv, u16x8 vv) {
#pragma unroll
    for (int j = 0; j < 8; ++j) {
      Q [sb + j] = bf2f((unsigned short)qv[j]);
      Kk[sb + j] = bf2f((unsigned short)kv[j]);
      V [sb + j] = bf2f((unsigned short)vv[j]);
    }
  };
  auto attend = [&](unsigned short* outp) {
    // lane (h,e): score = q[h].k[e] / 8
    float s = 0.f;
#pragma unroll
    for (int d = 0; d < 64; ++d) s += Q[h * 68 + d] * Kk[e * 68 + d];
    s *= 0.125f;
    float m = fmaxf(s, __shfl_xor(s, 1, 8));
    m = fmaxf(m, __shfl_xor(m, 2, 8));
    m = fmaxf(m, __shfl_xor(m, 4, 8));
    const float p = __expf(s - m);
    float su = p;
    su += __shfl_xor(su, 1, 8); su += __shfl_xor(su, 2, 8); su += __shfl_xor(su, 4, 8);
    ATT[lane] = p / su;
    // out[h][d0+j] = sum_e attn[h,e] * v[e][d0+j]
    float o[8];
    const int d0 = (lane & 7) * 8;
#pragma unroll
    for (int j = 0; j < 8; ++j) {
      float a = 0.f;
#pragma unroll
      for (int e2 = 0; e2 < 8; ++e2) a += ATT[h * 8 + e2] * V[e2 * 68 + d0 + j];
      o[j] = a;
    }
    u16x8 ob;
#pragma unroll
    for (int j = 0; j < 8; ++j) ob[j] = f2bf(o[j]);
    *(u16x8*)(outp + l8) = ob;   // contiguous 16B store, col = lane*8+j
  };

  stage(q1, k1, v1);
  attend(rp);            // direction 1 -> att1 over q1 segment
  stage(q2, k2, v2);
  attend(rl);            // direction 2 -> att2 over k1 segment
}

// ---------------------------------------------------------------------------
extern "C" void kernel_launch(void* const* d_in, const int* in_sizes, int n_in,
                              void* d_out, int out_size, void* d_ws, size_t ws_size,
                              hipStream_t stream)
{
  const float* xp  = (const float*)d_in[0];
  const float* xl  = (const float*)d_in[1];
  const float* Wq1 = (const float*)d_in[2];   const float* bq1 = (const float*)d_in[3];
  const float* Wk1 = (const float*)d_in[4];   const float* bk1 = (const float*)d_in[5];
  const float* Wv1 = (const float*)d_in[6];   const float* bv1 = (const float*)d_in[7];
  const float* Wq2 = (const float*)d_in[8];   const float* bq2 = (const float*)d_in[9];
  const float* Wk2 = (const float*)d_in[10];  const float* bk2 = (const float*)d_in[11];
  const float* Wv2 = (const float*)d_in[12];  const float* bv2 = (const float*)d_in[13];
  const float* Wo1 = (const float*)d_in[14];  const float* bo1 = (const float*)d_in[15];
  const float* Wo2 = (const float*)d_in[16];  const float* bo2 = (const float*)d_in[17];

  char* p = (char*)d_ws;
  unsigned short* Wp   = (unsigned short*)p; p += (size_t)786432 * 2;
  unsigned short* Wl   = (unsigned short*)p; p += (size_t)786432 * 2;
  unsigned short* Wo1b = (unsigned short*)p; p += (size_t)262144 * 2;
  unsigned short* Wo2b = (unsigned short*)p; p += (size_t)262144 * 2;
  float*          bp   = (float*)p;          p += (size_t)1536 * 4;
  float*          bl   = (float*)p;          p += (size_t)1536 * 4;
  unsigned short* qkvp = (unsigned short*)p; p += (size_t)B_ROWS * NP * 2;
  unsigned short* qkvl = (unsigned short*)p; p += (size_t)B_ROWS * NP * 2;
  (void)ws_size; (void)in_sizes; (void)n_in; (void)out_size;

  pack_kernel<<<2048, 256, 0, stream>>>(Wq1, Wk1, Wv1, Wq2, Wk2, Wv2, Wo1, Wo2,
                                        bq1, bk1, bv1, bq2, bk2, bv2,
                                        Wp, Wl, Wo1b, Wo2b, bp, bl);

  // qkv projections: [32768 x 1536] = x @ Wpack^T + bpack   (bf16 out)
  gemm_kernel<true, false><<<3072, 256, 0, stream>>>(xp, 512, Wp, bp, qkvp, NP, 12);
  gemm_kernel<true, false><<<3072, 256, 0, stream>>>(xl, 512, Wl, bl, qkvl, NP, 12);

  // per-row attention, both directions (writes att1/att2 in place)
  attn_kernel<<<8192, 256, 0, stream>>>(qkvp, qkvl);

  // output projections -> fp32 outputs
  float* out_p = (float*)d_out;
  float* out_l = out_p + (size_t)B_ROWS * 512;
  gemm_kernel<false, true><<<1024, 256, 0, stream>>>(qkvp, NP, Wo1b, bo1, out_p, 512, 4);
  gemm_kernel<false, true><<<1024, 256, 0, stream>>>(qkvl, NP, Wo2b, bo2, out_l, 512, 4);
}

// Round 2
// 502.225 us; speedup vs baseline: 1.0985x; 1.0985x over previous
//
#include <hip/hip_runtime.h>
#include <hip/hip_bf16.h>

// Problem constants
#define B_ROWS 32768
#define K_DIM  512
#define NP     1536   // packed qkv width per input

typedef __attribute__((ext_vector_type(8))) short          bf16x8;
typedef __attribute__((ext_vector_type(8))) unsigned short u16x8;
typedef __attribute__((ext_vector_type(4))) unsigned short u16x4;
typedef __attribute__((ext_vector_type(4))) float          f32x4;

static __device__ __forceinline__ unsigned short f2bf(float f) {
  __hip_bfloat16 h = __float2bfloat16(f);
  unsigned short u; __builtin_memcpy(&u, &h, 2); return u;
}
static __device__ __forceinline__ float bf2f(unsigned short u) {
  unsigned int x = ((unsigned int)u) << 16; float f; __builtin_memcpy(&f, &x, 4); return f;
}

// async global->LDS, 16B per lane. Dest base must be wave-uniform; HW adds lane*16B.
static __device__ __forceinline__ void gload_lds16(const void* g, void* l) {
  __builtin_amdgcn_global_load_lds(
      (const __attribute__((address_space(1))) void*)g,
      (__attribute__((address_space(3))) void*)l, 16, 0, 0);
}

// ---------------------------------------------------------------------------
// K0: pack weights to bf16 (row-major [n][k], MFMA-B-ready) + pack biases fp32
//   Wp = [Wq1; Wk2; Wv2]  (protein-input projections)
//   Wl = [Wk1; Wv1; Wq2]  (ligand-input projections)
// ---------------------------------------------------------------------------
__global__ __launch_bounds__(256) void pack_kernel(
    const float* __restrict__ Wq1, const float* __restrict__ Wk1,
    const float* __restrict__ Wv1, const float* __restrict__ Wq2,
    const float* __restrict__ Wk2, const float* __restrict__ Wv2,
    const float* __restrict__ Wo1, const float* __restrict__ Wo2,
    const float* __restrict__ bq1, const float* __restrict__ bk1,
    const float* __restrict__ bv1, const float* __restrict__ bq2,
    const float* __restrict__ bk2, const float* __restrict__ bv2,
    unsigned short* __restrict__ Wp, unsigned short* __restrict__ Wl,
    unsigned short* __restrict__ Wo1b, unsigned short* __restrict__ Wo2b,
    float* __restrict__ bp, float* __restrict__ bl)
{
  const int gid = blockIdx.x * 256 + threadIdx.x;   // 524288 threads
  const int idx = gid * 4;                          // 4 floats each
  const float* src; unsigned short* dst;
  if (idx < 786432) {                               // Wp
    int n = idx >> 9, k = idx & 511;
    const float* W = (n < 512) ? (Wq1 + (size_t)n * 512)
                   : (n < 1024) ? (Wk2 + (size_t)(n - 512) * 512)
                                : (Wv2 + (size_t)(n - 1024) * 512);
    src = W + k; dst = Wp + idx;
  } else if (idx < 1572864) {                       // Wl
    int r = idx - 786432; int n = r >> 9, k = r & 511;
    const float* W = (n < 512) ? (Wk1 + (size_t)n * 512)
                   : (n < 1024) ? (Wv1 + (size_t)(n - 512) * 512)
                                : (Wq2 + (size_t)(n - 1024) * 512);
    src = W + k; dst = Wl + r;
  } else if (idx < 1835008) {                       // Wo1
    int r = idx - 1572864; src = Wo1 + r; dst = Wo1b + r;
  } else {                                          // Wo2
    int r = idx - 1835008; src = Wo2 + r; dst = Wo2b + r;
  }
  float4 v = *reinterpret_cast<const float4*>(src);
  u16x4 o; o[0] = f2bf(v.x); o[1] = f2bf(v.y); o[2] = f2bf(v.z); o[3] = f2bf(v.w);
  *reinterpret_cast<u16x4*>(dst) = o;

  if (gid < 1536) {
    int n = gid;
    bp[n] = (n < 512) ? bq1[n] : (n < 1024) ? bk2[n - 512] : bv2[n - 1024];
  } else if (gid < 3072) {
    int n = gid - 1536;
    bl[n] = (n < 512) ? bk1[n] : (n < 1024) ? bv1[n - 512] : bq2[n - 1024];
  }
}

// ---------------------------------------------------------------------------
// K0b: fp32 -> bf16 convert of the two activation matrices (once, up front).
//   Removes the per-K-step, per-N-tile (x12) reg-staged fp32->bf16 conversion
//   from the qkv GEMM inner loop so A can use global_load_lds like B.
//   grid 16384 x 256, 8 elems/thread: 2 x 16,777,216 elems exactly.
// ---------------------------------------------------------------------------
__global__ __launch_bounds__(256) void cvt_kernel(
    const float* __restrict__ xp, const float* __restrict__ xl,
    unsigned short* __restrict__ xpb, unsigned short* __restrict__ xlb)
{
  const size_t gid = (size_t)blockIdx.x * 256 + threadIdx.x;
  size_t i = gid * 8;
  const float* src; unsigned short* dst;
  if (i < 16777216) { src = xp + i; dst = xpb + i; }
  else              { src = xl + (i - 16777216); dst = xlb + (i - 16777216); }
  float4 a = ((const float4*)src)[0];
  float4 b = ((const float4*)src)[1];
  u16x8 o;
  o[0] = f2bf(a.x); o[1] = f2bf(a.y); o[2] = f2bf(a.z); o[3] = f2bf(a.w);
  o[4] = f2bf(b.x); o[5] = f2bf(b.y); o[6] = f2bf(b.z); o[7] = f2bf(b.w);
  *(u16x8*)dst = o;
}

// ---------------------------------------------------------------------------
// GEMM: C[m][n] = sum_k A[m][k] * W[n][k] + bias[n]
//   m97-proven structure: 128x128 tile, BK=32, 256 threads (4 waves, 2x2),
//   MFMA 16x16x32 bf16, BOTH operands staged via global_load_lds width=16
//   (linear dest: LDS short-offset = r*2048 + w*512 + lane*8  <=>
//    row = t>>2, col = (t&3)*8 for t = r*256+tid  -- proven in R1 via B path).
// ---------------------------------------------------------------------------
template<bool OUT_F32>
__global__ __launch_bounds__(256, 2)
void gemm_kernel(const unsigned short* __restrict__ Aptr, int lda,
                 const unsigned short* __restrict__ Wb,
                 const float* __restrict__ bias,
                 void* __restrict__ Cptr, int ldc,
                 int ntiles)
{
  __shared__ __align__(16) unsigned short As[128 * 32];
  __shared__ __align__(16) unsigned short Bs[128 * 32];

  // bijective XCD swizzle (gridDim.x % 8 == 0 guaranteed by launch)
  const int nwg = gridDim.x;
  const int cpx = nwg >> 3;
  const int b0  = blockIdx.x;
  const int wk  = (b0 & 7) * cpx + (b0 >> 3);
  const int mt  = wk / ntiles, nt = wk - mt * ntiles;
  const int m0  = mt << 7, n0 = nt << 7;

  const int tid = threadIdx.x;
  const int lane = tid & 63, w = tid >> 6;
  const int wm = w >> 1, wn = w & 1;
  const int fr = lane & 15, fk = lane >> 4;     // frag row, k-chunk select

  f32x4 acc[4][4] = {};

  for (int kk = 0; kk < 512; kk += 32) {
    // stage B tile [128n x 32k] + A tile [128m x 32k], 2 rounds each
#pragma unroll
    for (int r = 0; r < 2; ++r) {
      const int t = r * 256 + tid;
      gload_lds16(Wb + (size_t)(n0 + (t >> 2)) * 512 + kk + (t & 3) * 8,
                  &Bs[r * 2048 + w * 512]);
    }
#pragma unroll
    for (int r = 0; r < 2; ++r) {
      const int t = r * 256 + tid;
      gload_lds16(Aptr + (size_t)(m0 + (t >> 2)) * lda + kk + (t & 3) * 8,
                  &As[r * 2048 + w * 512]);
    }
    __syncthreads();   // drains vmcnt (global_load_lds)

    bf16x8 af[4], bfr[4];
#pragma unroll
    for (int i = 0; i < 4; ++i) {
      af[i]  = *(const bf16x8*)&As[(wm * 64 + i * 16 + fr) * 32 + fk * 8];
      bfr[i] = *(const bf16x8*)&Bs[(wn * 64 + i * 16 + fr) * 32 + fk * 8];
    }
#pragma unroll
    for (int mi = 0; mi < 4; ++mi)
#pragma unroll
      for (int ni = 0; ni < 4; ++ni)
        acc[mi][ni] = __builtin_amdgcn_mfma_f32_16x16x32_bf16(af[mi], bfr[ni], acc[mi][ni], 0, 0, 0);
    __syncthreads();
  }

  // epilogue: bias add, store. C layout: col = lane&15, row = (lane>>4)*4 + j
#pragma unroll
  for (int ni = 0; ni < 4; ++ni) {
    const int col = n0 + wn * 64 + ni * 16 + fr;
    const float bv = bias[col];
#pragma unroll
    for (int mi = 0; mi < 4; ++mi) {
      const int rbase = m0 + wm * 64 + mi * 16 + fk * 4;
#pragma unroll
      for (int j = 0; j < 4; ++j) {
        const float v = acc[mi][ni][j] + bv;
        if (OUT_F32)
          ((float*)Cptr)[(size_t)(rbase + j) * ldc + col] = v;
        else
          ((unsigned short*)Cptr)[(size_t)(rbase + j) * ldc + col] = f2bf(v);
      }
    }
  }
}

// ---------------------------------------------------------------------------
// K2: per-row head-mixing attention, both directions. 1 wave = 1 row.
//   qkvp rows: [q1 | k2 | v2], qkvl rows: [k1 | v1 | q2] (bf16, stride 1536).
//   att1 overwrites qkvp[:,0:512], att2 overwrites qkvl[:,0:512].
// ---------------------------------------------------------------------------
__global__ __launch_bounds__(256, 4)
void attn_kernel(unsigned short* __restrict__ qkvp, unsigned short* __restrict__ qkvl)
{
  __shared__ float lds[4][1696];  // per wave: Q[8][68], K[8][68], V[8][68], ATT[64]
  const int w = threadIdx.x >> 6, lane = threadIdx.x & 63;
  const size_t r = (size_t)blockIdx.x * 4 + w;
  unsigned short* rp = qkvp + r * NP;
  unsigned short* rl = qkvl + r * NP;
  const int l8 = lane * 8;

  // load all six 512-wide row segments up-front (16B/lane each, coalesced)
  u16x8 q1 = *(const u16x8*)(rp + l8);
  u16x8 k2 = *(const u16x8*)(rp + 512 + l8);
  u16x8 v2 = *(const u16x8*)(rp + 1024 + l8);
  u16x8 k1 = *(const u16x8*)(rl + l8);
  u16x8 v1 = *(const u16x8*)(rl + 512 + l8);
  u16x8 q2 = *(const u16x8*)(rl + 1024 + l8);

  float* Q   = &lds[w][0];
  float* Kk  = Q + 544;
  float* V   = Kk + 544;
  float* ATT = V + 544;
  const int h = lane >> 3, e = lane & 7;
  const int sb = h * 68 + (lane & 7) * 8;   // this lane's 8 elems: head=lane>>3, d=(lane&7)*8

  auto stage = [&](u16x8 qv, u16x8 kv, u16x8 vv) {
#pragma unroll
    for (int j = 0; j < 8; ++j) {
      Q [sb + j] = bf2f((unsigned short)qv[j]);
      Kk[sb + j] = bf2f((unsigned short)kv[j]);
      V [sb + j] = bf2f((unsigned short)vv[j]);
    }
  };
  auto attend = [&](unsigned short* outp) {
    // lane (h,e): score = q[h].k[e] / 8
    float s = 0.f;
#pragma unroll
    for (int d = 0; d < 64; ++d) s += Q[h * 68 + d] * Kk[e * 68 + d];
    s *= 0.125f;
    float m = fmaxf(s, __shfl_xor(s, 1, 8));
    m = fmaxf(m, __shfl_xor(m, 2, 8));
    m = fmaxf(m, __shfl_xor(m, 4, 8));
    const float p = __expf(s - m);
    float su = p;
    su += __shfl_xor(su, 1, 8); su += __shfl_xor(su, 2, 8); su += __shfl_xor(su, 4, 8);
    ATT[lane] = p / su;
    // out[h][d0+j] = sum_e attn[h,e] * v[e][d0+j]
    float o[8];
    const int d0 = (lane & 7) * 8;
#pragma unroll
    for (int j = 0; j < 8; ++j) {
      float a = 0.f;
#pragma unroll
      for (int e2 = 0; e2 < 8; ++e2) a += ATT[h * 8 + e2] * V[e2 * 68 + d0 + j];
      o[j] = a;
    }
    u16x8 ob;
#pragma unroll
    for (int j = 0; j < 8; ++j) ob[j] = f2bf(o[j]);
    *(u16x8*)(outp + l8) = ob;   // contiguous 16B store, col = lane*8+j
  };

  stage(q1, k1, v1);
  attend(rp);            // direction 1 -> att1 over q1 segment
  stage(q2, k2, v2);
  attend(rl);            // direction 2 -> att2 over k1 segment
}

// ---------------------------------------------------------------------------
extern "C" void kernel_launch(void* const* d_in, const int* in_sizes, int n_in,
                              void* d_out, int out_size, void* d_ws, size_t ws_size,
                              hipStream_t stream)
{
  const float* xp  = (const float*)d_in[0];
  const float* xl  = (const float*)d_in[1];
  const float* Wq1 = (const float*)d_in[2];   const float* bq1 = (const float*)d_in[3];
  const float* Wk1 = (const float*)d_in[4];   const float* bk1 = (const float*)d_in[5];
  const float* Wv1 = (const float*)d_in[6];   const float* bv1 = (const float*)d_in[7];
  const float* Wq2 = (const float*)d_in[8];   const float* bq2 = (const float*)d_in[9];
  const float* Wk2 = (const float*)d_in[10];  const float* bk2 = (const float*)d_in[11];
  const float* Wv2 = (const float*)d_in[12];  const float* bv2 = (const float*)d_in[13];
  const float* Wo1 = (const float*)d_in[14];  const float* bo1 = (const float*)d_in[15];
  const float* Wo2 = (const float*)d_in[16];  const float* bo2 = (const float*)d_in[17];

  char* p = (char*)d_ws;
  unsigned short* Wp   = (unsigned short*)p; p += (size_t)786432 * 2;
  unsigned short* Wl   = (unsigned short*)p; p += (size_t)786432 * 2;
  unsigned short* Wo1b = (unsigned short*)p; p += (size_t)262144 * 2;
  unsigned short* Wo2b = (unsigned short*)p; p += (size_t)262144 * 2;
  float*          bp   = (float*)p;          p += (size_t)1536 * 4;
  float*          bl   = (float*)p;          p += (size_t)1536 * 4;
  unsigned short* qkvp = (unsigned short*)p; p += (size_t)B_ROWS * NP * 2;
  unsigned short* qkvl = (unsigned short*)p; p += (size_t)B_ROWS * NP * 2;
  (void)ws_size; (void)in_sizes; (void)n_in; (void)out_size;

  // bf16 activations live in d_out (67 MB of its 128 MB) until the out-proj
  // GEMMs overwrite it at the end -- zero extra workspace, no alias overlap.
  unsigned short* xpb = (unsigned short*)d_out;
  unsigned short* xlb = xpb + (size_t)B_ROWS * 512;

  pack_kernel<<<2048, 256, 0, stream>>>(Wq1, Wk1, Wv1, Wq2, Wk2, Wv2, Wo1, Wo2,
                                        bq1, bk1, bv1, bq2, bk2, bv2,
                                        Wp, Wl, Wo1b, Wo2b, bp, bl);
  cvt_kernel<<<16384, 256, 0, stream>>>(xp, xl, xpb, xlb);

  // qkv projections: [32768 x 1536] = x @ Wpack^T + bpack   (bf16 out)
  gemm_kernel<false><<<3072, 256, 0, stream>>>(xpb, 512, Wp, bp, qkvp, NP, 12);
  gemm_kernel<false><<<3072, 256, 0, stream>>>(xlb, 512, Wl, bl, qkvl, NP, 12);

  // per-row attention, both directions (writes att1/att2 in place)
  attn_kernel<<<8192, 256, 0, stream>>>(qkvp, qkvl);

  // output projections -> fp32 outputs (overwrite the xpb/xlb scratch region)
  float* out_p = (float*)d_out;
  float* out_l = out_p + (size_t)B_ROWS * 512;
  gemm_kernel<true><<<1024, 256, 0, stream>>>(qkvp, NP, Wo1b, bo1, out_p, 512, 4);
  gemm_kernel<true><<<1024, 256, 0, stream>>>(qkvl, NP, Wo2b, bo2, out_l, 512, 4);
}